// Round 2
// 505.879 us; speedup vs baseline: 1.0497x; 1.0497x over previous
//
#include <hip/hip_runtime.h>
#include <hip/hip_bf16.h>
#include <stdint.h>

// CoAttention: B=64, C=1024, H=W=16 (N=256), CK=128.
#define B_  64
#define C_  1024
#define CK_ 128
#define N_  256

typedef __bf16 bf16;
typedef __attribute__((ext_vector_type(8))) __bf16 bf16x8;
typedef __attribute__((ext_vector_type(4))) __bf16 bf16x4;
typedef __attribute__((ext_vector_type(4))) float floatx4;

// ---- workspace layout (bytes) ----
constexpr size_t OFF_XBT = 0;                 // bf16 [64][256][1024]
constexpr size_t OFF_YBT = 33554432;
constexpr size_t OFF_WK1 = 67108864;          // bf16 [128][1024]
constexpr size_t OFF_WK2 = 67371008;
constexpr size_t OFF_WV1 = 67633152;          // bf16 [1024][1024]
constexpr size_t OFF_WV2 = 69730304;
constexpr size_t OFF_KXT = 71827456;          // bf16 [64][256][128]
constexpr size_t OFF_KYT = 76021760;
constexpr size_t OFF_AX  = 71827456;          // bf16 [64][256][256] aliases kxT/kyT
constexpr size_t OFF_AY  = 80216064;
constexpr size_t WS_NEEDED = 88604672;

__device__ __forceinline__ void async16(const void* g, void* l) {
  __builtin_amdgcn_global_load_lds((const __attribute__((address_space(1))) void*)g,
                                   (__attribute__((address_space(3))) void*)l, 16, 0, 0);
}

// fp32 [C][N] -> bf16 [N][C] transpose; z<64: x-tensor, else y-tensor
__global__ __launch_bounds__(256) void k_xpose(const float* __restrict__ xin,
                                               const float* __restrict__ yin,
                                               bf16* __restrict__ xo, bf16* __restrict__ yo) {
  __shared__ float tile[64][65];
  int nt = blockIdx.x, ct = blockIdx.y, z = blockIdx.z;
  int b = z & 63;
  const float* in = (z < 64) ? xin : yin;
  bf16* out = (z < 64) ? xo : yo;
  const float* src = in + (size_t)b * C_ * N_ + (size_t)ct * 64 * N_ + nt * 64;
  bf16* dst = out + (size_t)b * N_ * C_ + (size_t)nt * 64 * C_ + ct * 64;
  int c4 = (threadIdx.x & 15) * 4, r0 = threadIdx.x >> 4;
#pragma unroll
  for (int i = 0; i < 4; ++i) {
    int r = r0 + i * 16;                       // c-local row
    float4 v = *(const float4*)(src + r * N_ + c4);
    tile[r][c4 + 0] = v.x; tile[r][c4 + 1] = v.y;
    tile[r][c4 + 2] = v.z; tile[r][c4 + 3] = v.w;
  }
  __syncthreads();
#pragma unroll
  for (int i = 0; i < 4; ++i) {
    int r = r0 + i * 16;                       // n-local row
    bf16x4 o;
    o[0] = (bf16)tile[c4 + 0][r]; o[1] = (bf16)tile[c4 + 1][r];
    o[2] = (bf16)tile[c4 + 2][r]; o[3] = (bf16)tile[c4 + 3][r];
    *(bf16x4*)(dst + (size_t)r * C_ + c4) = o;
  }
}

// two fp32->bf16 conversions in one launch
__global__ __launch_bounds__(256) void k_cvt2(const float* __restrict__ inA,
                                              const float* __restrict__ inB,
                                              bf16* __restrict__ outA, bf16* __restrict__ outB,
                                              int n4each) {
  int i = blockIdx.x * 256 + threadIdx.x;
  const float* in = (i < n4each) ? inA : inB;
  bf16* out = (i < n4each) ? outA : outB;
  int j = (i < n4each) ? i : (i - n4each);
  if (i < 2 * n4each) {
    float4 v = ((const float4*)in)[j];
    bf16x4 o;
    o[0] = (bf16)v.x; o[1] = (bf16)v.y; o[2] = (bf16)v.z; o[3] = (bf16)v.w;
    ((bf16x4*)out)[j] = o;
  }
}

// 128x128 GEMM core, 3-buffer LDS pipeline, raw s_barrier + counted vmcnt
// (never drains vmcnt to 0 in steady state; prefetch depth 2).
// LDS: As[buf] @ buf*8192 (8KB each, buf=0..2), Bs[buf] @ 24576 + buf*8192.
// smem must be 48KB. One barrier per k-step; buffer (kt+2)%3 overwritten at
// step kt was last read at step kt-1, protected by step-kt barrier.
template <int KITERS>
__device__ __forceinline__ void gemm128_core(const bf16* __restrict__ Ag, int ldA,
                                             const bf16* __restrict__ Bg, int ldB,
                                             char* smem, floatx4 (&acc)[4][4]) {
  const int tid = threadIdx.x;
  const int l = tid & 63, wid = tid >> 6;
  const int wm = wid & 1, wn = wid >> 1;
  auto issue = [&](int kt, int buf) {
    const int k0 = kt * 32;
#pragma unroll
    for (int s = 0; s < 2; ++s) {
      int row = (s << 6) + (wid << 4) + (l >> 2);
      int q = (l & 3) ^ ((row >> 1) & 3);
      async16(Ag + (size_t)row * ldA + k0 + q * 8, smem + buf * 8192 + (s << 12) + (wid << 10));
      async16(Bg + (size_t)row * ldB + k0 + q * 8, smem + 24576 + buf * 8192 + (s << 12) + (wid << 10));
    }
  };
  auto compute = [&](int buf) {
    const char* As = smem + buf * 8192;
    const char* Bs = smem + 24576 + buf * 8192;
    bf16x8 af[4], bfr[4];
#pragma unroll
    for (int t = 0; t < 4; ++t) {
      int m = (wm << 6) + t * 16 + (l & 15);
      af[t] = *(const bf16x8*)(As + m * 64 + (((l >> 4) ^ ((m >> 1) & 3)) << 4));
      int n = (wn << 6) + t * 16 + (l & 15);
      bfr[t] = *(const bf16x8*)(Bs + n * 64 + (((l >> 4) ^ ((n >> 1) & 3)) << 4));
    }
#pragma unroll
    for (int tm = 0; tm < 4; ++tm)
#pragma unroll
      for (int tn = 0; tn < 4; ++tn)
        acc[tm][tn] = __builtin_amdgcn_mfma_f32_16x16x32_bf16(af[tm], bfr[tn], acc[tm][tn], 0, 0, 0);
  };
  issue(0, 0);
  if (KITERS > 1) issue(1, 1);
#pragma unroll
  for (int kt = 0; kt < KITERS; ++kt) {
    // own loads for step kt done; step kt+1's 4 ops stay in flight across barrier
    if (kt + 1 < KITERS) asm volatile("s_waitcnt vmcnt(4) lgkmcnt(0)" ::: "memory");
    else                 asm volatile("s_waitcnt vmcnt(0) lgkmcnt(0)" ::: "memory");
    __builtin_amdgcn_s_barrier();
    asm volatile("" ::: "memory");          // keep loads/ds_reads below the barrier
    if (kt + 2 < KITERS) issue(kt + 2, (kt + 2) % 3);
    __builtin_amdgcn_s_setprio(1);
    compute(kt % 3);
    __builtin_amdgcn_s_setprio(0);
  }
}

// kT[n][o] = sum_c xbT[n][c]*wk[o][c] + bk[o]
__global__ __launch_bounds__(256) void k_projk(
    const bf16* __restrict__ xbT, const bf16* __restrict__ ybT,
    const bf16* __restrict__ wk1b, const bf16* __restrict__ wk2b,
    const float* __restrict__ bk1, const float* __restrict__ bk2,
    bf16* __restrict__ kxT, bf16* __restrict__ kyT) {
  __shared__ __align__(16) char smem[49152];
  int mt = blockIdx.x, br = blockIdx.y, b = blockIdx.z;
  const bf16* A = (br ? ybT : xbT) + (size_t)b * N_ * C_ + (size_t)mt * 128 * C_;
  const bf16* Bt = br ? wk2b : wk1b;
  const float* bias = br ? bk2 : bk1;
  bf16* out = (br ? kyT : kxT) + (size_t)b * N_ * CK_ + (size_t)mt * 128 * CK_;
  floatx4 acc[4][4];
  floatx4 z = {0.f, 0.f, 0.f, 0.f};
#pragma unroll
  for (int i = 0; i < 4; ++i)
#pragma unroll
    for (int j = 0; j < 4; ++j) acc[i][j] = z;
  gemm128_core<32>(A, C_, Bt, C_, smem, acc);
  const int l = threadIdx.x & 63, wid = threadIdx.x >> 6;
  const int wm = wid & 1, wn = wid >> 1;
#pragma unroll
  for (int tn = 0; tn < 4; ++tn) {
    int oc = (wn << 6) + tn * 16 + (l & 15);
    float bkv = bias[oc];
#pragma unroll
    for (int tm = 0; tm < 4; ++tm)
#pragma unroll
      for (int r = 0; r < 4; ++r) {
        int row = (wm << 6) + tm * 16 + ((l >> 4) << 2) + r;
        out[row * CK_ + oc] = (bf16)(acc[tm][tn][r] + bkv);
      }
  }
}

// E[m][n] = sum_o kxT[m][o]*kyT[n][o]
__global__ __launch_bounds__(256) void k_energy(const bf16* __restrict__ kxT,
                                                const bf16* __restrict__ kyT,
                                                float* __restrict__ E) {
  __shared__ __align__(16) char smem[49152];
  int mt = blockIdx.x, nt = blockIdx.y, b = blockIdx.z;
  const bf16* A = kxT + (size_t)b * N_ * CK_ + (size_t)mt * 128 * CK_;
  const bf16* Bt = kyT + (size_t)b * N_ * CK_ + (size_t)nt * 128 * CK_;
  float* out = E + (size_t)b * N_ * N_ + (size_t)mt * 128 * N_ + nt * 128;
  floatx4 acc[4][4];
  floatx4 z = {0.f, 0.f, 0.f, 0.f};
#pragma unroll
  for (int i = 0; i < 4; ++i)
#pragma unroll
    for (int j = 0; j < 4; ++j) acc[i][j] = z;
  gemm128_core<4>(A, CK_, Bt, CK_, smem, acc);
  const int l = threadIdx.x & 63, wid = threadIdx.x >> 6;
  const int wm = wid & 1, wn = wid >> 1;
#pragma unroll
  for (int tm = 0; tm < 4; ++tm)
#pragma unroll
    for (int tn = 0; tn < 4; ++tn)
#pragma unroll
      for (int r = 0; r < 4; ++r) {
        int row = (wm << 6) + tm * 16 + ((l >> 4) << 2) + r;
        int col = (wn << 6) + tn * 16 + (l & 15);
        out[row * N_ + col] = acc[tm][tn][r];
      }
}

// ax[m][n] = softmax_n E[m][n]; ay[i][j] = softmax over first index: exp(E[j][i]-cmax_i)*crcp_i
// grid (64 b, 4 q): block handles rows/cols q*64..q*64+64
__global__ __launch_bounds__(256) void k_softmax(const float* __restrict__ E,
                                                 bf16* __restrict__ ax,
                                                 bf16* __restrict__ ay) {
  __shared__ float slabT[64][257];   // [col-local][row]
  __shared__ float red[16][64];
  __shared__ float cmaxS[64], crcpS[64], rmaxS[64], rrcpS[64];
  const int b = blockIdx.x, q = blockIdx.y;
  const float* e = E + (size_t)b * N_ * N_;
  const int tid = threadIdx.x, l = tid & 63, wid = tid >> 6;
  const int cg = tid & 15;          // 4-col group
  const int rg = tid >> 4;          // 16 row groups
  // phase 1: load slab E[:, q*64..+64], transpose into slabT, partial col max
  float m4[4] = {-1e30f, -1e30f, -1e30f, -1e30f};
#pragma unroll 4
  for (int k = 0; k < 16; ++k) {
    int r = rg + (k << 4);
    float4 v = *(const float4*)(e + (size_t)r * N_ + q * 64 + cg * 4);
    slabT[cg * 4 + 0][r] = v.x; slabT[cg * 4 + 1][r] = v.y;
    slabT[cg * 4 + 2][r] = v.z; slabT[cg * 4 + 3][r] = v.w;
    m4[0] = fmaxf(m4[0], v.x); m4[1] = fmaxf(m4[1], v.y);
    m4[2] = fmaxf(m4[2], v.z); m4[3] = fmaxf(m4[3], v.w);
  }
#pragma unroll
  for (int j = 0; j < 4; ++j) red[rg][cg * 4 + j] = m4[j];
  __syncthreads();
  if (tid < 64) {
    float mm = red[0][tid];
#pragma unroll
    for (int i = 1; i < 16; ++i) mm = fmaxf(mm, red[i][tid]);
    cmaxS[tid] = mm;
  }
  __syncthreads();
  // phase 2: col sum of exp (from slabT)
  float s4[4] = {0.f, 0.f, 0.f, 0.f};
#pragma unroll 4
  for (int k = 0; k < 16; ++k) {
    int r = rg + (k << 4);
#pragma unroll
    for (int j = 0; j < 4; ++j) s4[j] += __expf(slabT[cg * 4 + j][r] - cmaxS[cg * 4 + j]);
  }
  __syncthreads();
#pragma unroll
  for (int j = 0; j < 4; ++j) red[rg][cg * 4 + j] = s4[j];
  __syncthreads();
  if (tid < 64) {
    float ss = 0.f;
#pragma unroll
    for (int i = 0; i < 16; ++i) ss += red[i][tid];
    crcpS[tid] = 1.0f / ss;
  }
  // phase 3: row stats for rows q*64..+64 (wave per row, shuffle reduce)
  for (int m = wid; m < 64; m += 4) {
    const float* row = e + (size_t)(q * 64 + m) * N_;
    float v0 = row[l], v1 = row[l + 64], v2 = row[l + 128], v3 = row[l + 192];
    float mx = fmaxf(fmaxf(v0, v1), fmaxf(v2, v3));
#pragma unroll
    for (int off = 32; off > 0; off >>= 1) mx = fmaxf(mx, __shfl_xor(mx, off));
    float s = __expf(v0 - mx) + __expf(v1 - mx) + __expf(v2 - mx) + __expf(v3 - mx);
#pragma unroll
    for (int off = 32; off > 0; off >>= 1) s += __shfl_xor(s, off);
    if (l == 0) { rmaxS[m] = mx; rrcpS[m] = 1.0f / s; }
  }
  __syncthreads();
  // phase 4: ax rows (float4 read, bf16x4 store)
  bf16* axb = ax + (size_t)b * N_ * N_;
#pragma unroll 4
  for (int t = 0; t < 16; ++t) {
    int rr = wid * 16 + t;
    float rm = rmaxS[rr], rc = rrcpS[rr];
    float4 v = *(const float4*)(e + (size_t)(q * 64 + rr) * N_ + l * 4);
    bf16x4 o;
    o[0] = (bf16)(__expf(v.x - rm) * rc); o[1] = (bf16)(__expf(v.y - rm) * rc);
    o[2] = (bf16)(__expf(v.z - rm) * rc); o[3] = (bf16)(__expf(v.w - rm) * rc);
    *(bf16x4*)(axb + (size_t)(q * 64 + rr) * N_ + l * 4) = o;
  }
  // phase 5: ay rows i=q*64+rr from slabT column-stats (conflict-free: lane l -> col l+64k)
  bf16* ayb = ay + (size_t)b * N_ * N_;
#pragma unroll 4
  for (int t = 0; t < 16; ++t) {
    int rr = wid * 16 + t;
    float cm = cmaxS[rr], cc = crcpS[rr];
#pragma unroll
    for (int k = 0; k < 4; ++k) {
      int j = l + 64 * k;
      ayb[(size_t)(q * 64 + rr) * N_ + j] = (bf16)(__expf(slabT[rr][j] - cm) * cc);
    }
  }
}

// Fused V: v = wv@x + bv (K=1024, B-stream 3-buf LDS pipeline + A reg-prefetch,
// raw barriers + counted vmcnt), o = v @ attn^T (K=256, reg-prefetch, no barriers),
// out = gamma*o + x.
// LDS 48KB: GEMM1 Bs[buf] @ buf*16384 (buf=0..2); GEMM2 vt@0 (overlays b0/b1 after barrier).
__global__ __launch_bounds__(256, 3) void k_vapply(
    const bf16* __restrict__ xbT, const bf16* __restrict__ ybT,
    const bf16* __restrict__ wv1b, const bf16* __restrict__ wv2b,
    const float* __restrict__ bv1, const float* __restrict__ bv2,
    const bf16* __restrict__ ax, const bf16* __restrict__ ay,
    const float* __restrict__ xin0, const float* __restrict__ yin0,
    const float* __restrict__ g1, const float* __restrict__ g2,
    float* __restrict__ out) {
  __shared__ __align__(16) char smem[49152];
  // XCD-swizzled decode: all 32 blocks of a given b land on one XCD (id%8 heuristic)
  int id = blockIdx.x;
  int xcd = id & 7;
  int idx = id >> 3;                 // 0..255
  int b = xcd + ((idx >> 5) << 3);   // 0..63
  int inner = idx & 31;
  int ct = inner & 15, br = inner >> 4;

  const bf16* A1 = (br ? wv2b : wv1b) + (size_t)ct * 64 * C_;
  const bf16* Bt1 = (br ? ybT : xbT) + (size_t)b * N_ * C_;
  const float* bias = br ? bv2 : bv1;
  const bf16* attn = (br ? ay : ax) + (size_t)b * N_ * N_;
  const float* xin = (br ? yin0 : xin0) + (size_t)b * C_ * N_ + (size_t)ct * 64 * N_;
  float gamma = br ? g2[0] : g1[0];
  float* o = out + (size_t)br * B_ * C_ * N_ + (size_t)b * C_ * N_ + (size_t)ct * 64 * N_;
  const int tid = threadIdx.x, l = tid & 63, wid = tid >> 6;

  auto loadA = [&](int kt, bf16x8 (&af)[4]) {
    const bf16* p = A1 + (size_t)(l & 15) * C_ + kt * 32 + ((l >> 4) << 3);
#pragma unroll
    for (int t = 0; t < 4; ++t) af[t] = *(const bf16x8*)(p + (size_t)t * 16 * C_);
  };
  auto issueB = [&](int kt, int buf) {
    const int k0 = kt * 32;
#pragma unroll
    for (int s = 0; s < 4; ++s) {
      int row = (s << 6) + (wid << 4) + (l >> 2);
      int q = (l & 3) ^ ((row >> 1) & 3);
      async16(Bt1 + (size_t)row * C_ + k0 + q * 8, smem + buf * 16384 + (s << 12) + (wid << 10));
    }
  };
  floatx4 acc[4][4];
  floatx4 z = {0.f, 0.f, 0.f, 0.f};
#pragma unroll
  for (int i = 0; i < 4; ++i)
#pragma unroll
    for (int j = 0; j < 4; ++j) acc[i][j] = z;

  auto compute1 = [&](int buf, bf16x8 (&af)[4]) {
    const char* Bs = smem + buf * 16384;
    bf16x8 bfr[4];
#pragma unroll
    for (int t = 0; t < 4; ++t) {
      int n = (wid << 6) + t * 16 + (l & 15);
      bfr[t] = *(const bf16x8*)(Bs + n * 64 + (((l >> 4) ^ ((n >> 1) & 3)) << 4));
    }
#pragma unroll
    for (int tm = 0; tm < 4; ++tm)
#pragma unroll
      for (int tn = 0; tn < 4; ++tn)
        acc[tm][tn] = __builtin_amdgcn_mfma_f32_16x16x32_bf16(af[tm], bfr[tn], acc[tm][tn], 0, 0, 0);
  };

  // ---- GEMM1: v[64][256] over K=1024. 3 LDS buffers, prefetch depth 2,
  // raw s_barrier + vmcnt(8) (8 VMEM ops/step: 4 global_load_lds + 4 A-reg loads).
  // Buffer (kt+2)%3 written at step kt was last read at step kt-1 -> safe after
  // step-kt barrier. lgkmcnt(0) before barrier: no ds_read still sampling a
  // buffer when another wave's DMA lands in it.
  bf16x8 afA[4], afB[4], afC[4];
  issueB(0, 0); loadA(0, afA);
  issueB(1, 1); loadA(1, afB);
  auto step = [&](int kt, int buf, bf16x8 (&afU)[4], bf16x8 (&afN)[4], bool more1, bool more2) {
    if (more1) asm volatile("s_waitcnt vmcnt(8) lgkmcnt(0)" ::: "memory");
    else       asm volatile("s_waitcnt vmcnt(0) lgkmcnt(0)" ::: "memory");
    __builtin_amdgcn_s_barrier();
    asm volatile("" ::: "memory");        // keep loads/ds_reads below the barrier
    if (more2) { issueB(kt + 2, (buf + 2) % 3); loadA(kt + 2, afN); }
    __builtin_amdgcn_s_setprio(1);
    compute1(buf, afU);
    __builtin_amdgcn_s_setprio(0);
  };
  for (int kt = 0; kt < 30; kt += 3) {
    step(kt,     0, afA, afC, true, true);
    step(kt + 1, 1, afB, afA, true, true);
    step(kt + 2, 2, afC, afB, true, true);
  }
  step(30, 0, afA, afC, true, false);
  step(31, 1, afB, afA, false, false);
  __syncthreads();   // all Bs reads done; smem region becomes vt

  // ---- v += bias, cast bf16, swizzled into vt ----
  char* vt = smem;
#pragma unroll
  for (int tm = 0; tm < 4; ++tm)
#pragma unroll
    for (int r = 0; r < 4; ++r) {
      int rr = tm * 16 + ((l >> 4) << 2) + r;             // c-local 0..63
      float bkv = bias[ct * 64 + rr];
#pragma unroll
      for (int tn = 0; tn < 4; ++tn) {
        int n = (wid << 6) + tn * 16 + (l & 15);
        int ch = (n >> 3) ^ (rr & 7);
        *(bf16*)(vt + rr * 512 + ch * 16 + ((n & 7) << 1)) = (bf16)(acc[tm][tn][r] + bkv);
      }
    }

  auto loadB2 = [&](int kt, bf16x8 (&bb)[4]) {
    const bf16* p = attn + (size_t)((wid << 6) + (l & 15)) * N_ + kt * 32 + ((l >> 4) << 3);
#pragma unroll
    for (int t = 0; t < 4; ++t) bb[t] = *(const bf16x8*)(p + (size_t)t * 16 * N_);
  };
  auto compute2 = [&](int kt, bf16x8 (&bb)[4]) {
    bf16x8 af[4];
#pragma unroll
    for (int t = 0; t < 4; ++t) {
      int m = t * 16 + (l & 15);
      int ch = ((kt << 2) + (l >> 4)) ^ (m & 7);
      af[t] = *(const bf16x8*)(vt + m * 512 + (ch << 4));
    }
#pragma unroll
    for (int tm = 0; tm < 4; ++tm)
#pragma unroll
      for (int tn = 0; tn < 4; ++tn)
        acc[tm][tn] = __builtin_amdgcn_mfma_f32_16x16x32_bf16(af[tm], bb[tn], acc[tm][tn], 0, 0, 0);
  };

  // ---- GEMM2: o[64][256] = vt @ attn^T over K=256, reg-prefetch, no barriers ----
  bf16x8 bfA[4], bfB[4];
  loadB2(0, bfA);          // issued before barrier; drained by it
  __syncthreads();         // vt visible
#pragma unroll
  for (int i = 0; i < 4; ++i)
#pragma unroll
    for (int j = 0; j < 4; ++j) acc[i][j] = z;
  for (int kt = 0; kt < 8; kt += 2) {
    loadB2(kt + 1, bfB);
    compute2(kt, bfA);
    if (kt + 2 < 8) loadB2(kt + 2, bfA);
    compute2(kt + 1, bfB);
  }

  // ---- epilogue: out = gamma*o + x ----
#pragma unroll
  for (int tm = 0; tm < 4; ++tm)
#pragma unroll
    for (int tn = 0; tn < 4; ++tn)
#pragma unroll
      for (int r = 0; r < 4; ++r) {
        int rr = tm * 16 + ((l >> 4) << 2) + r;
        int m = (wid << 6) + tn * 16 + (l & 15);
        int idx2 = rr * N_ + m;
        o[idx2] = gamma * acc[tm][tn][r] + xin[idx2];
      }
}

__global__ __launch_bounds__(256) void k_fallback(const float4* __restrict__ x,
                                                  const float4* __restrict__ y,
                                                  float4* __restrict__ out) {
  size_t i = (size_t)blockIdx.x * 256 + threadIdx.x;
  out[i] = x[i];
  out[4194304 + i] = y[i];
}

extern "C" void kernel_launch(void* const* d_in, const int* in_sizes, int n_in,
                              void* d_out, int out_size, void* d_ws, size_t ws_size,
                              hipStream_t stream) {
  const float* x   = (const float*)d_in[0];
  const float* y   = (const float*)d_in[1];
  const float* wk1 = (const float*)d_in[2];
  const float* bk1 = (const float*)d_in[3];
  const float* wk2 = (const float*)d_in[4];
  const float* bk2 = (const float*)d_in[5];
  const float* wv1 = (const float*)d_in[6];
  const float* bv1 = (const float*)d_in[7];
  const float* wv2 = (const float*)d_in[8];
  const float* bv2 = (const float*)d_in[9];
  const float* g1  = (const float*)d_in[10];
  const float* g2  = (const float*)d_in[11];
  float* out = (float*)d_out;

  if (ws_size < WS_NEEDED) {
    k_fallback<<<16384, 256, 0, stream>>>((const float4*)x, (const float4*)y, (float4*)out);
    return;
  }

  char* ws = (char*)d_ws;
  bf16* xbT  = (bf16*)(ws + OFF_XBT);
  bf16* ybT  = (bf16*)(ws + OFF_YBT);
  bf16* wk1b = (bf16*)(ws + OFF_WK1);
  bf16* wk2b = (bf16*)(ws + OFF_WK2);
  bf16* wv1b = (bf16*)(ws + OFF_WV1);
  bf16* wv2b = (bf16*)(ws + OFF_WV2);
  bf16* kxT  = (bf16*)(ws + OFF_KXT);
  bf16* kyT  = (bf16*)(ws + OFF_KYT);
  bf16* axp  = (bf16*)(ws + OFF_AX);
  bf16* ayp  = (bf16*)(ws + OFF_AY);
  float* E = out + (size_t)B_ * C_ * N_;   // dead out_y region

  k_xpose<<<dim3(4, 16, 128), 256, 0, stream>>>(x, y, xbT, ybT);
  k_cvt2<<<256, 256, 0, stream>>>(wk1, wk2, wk1b, wk2b, 32768);
  k_cvt2<<<2048, 256, 0, stream>>>(wv1, wv2, wv1b, wv2b, 262144);
  k_projk<<<dim3(2, 2, 64), 256, 0, stream>>>(xbT, ybT, wk1b, wk2b, bk1, bk2, kxT, kyT);
  k_energy<<<dim3(2, 2, 64), 256, 0, stream>>>(kxT, kyT, E);
  k_softmax<<<dim3(64, 4), 256, 0, stream>>>(E, axp, ayp);
  k_vapply<<<2048, 256, 0, stream>>>(xbT, ybT, wv1b, wv2b, bv1, bv2,
                                     axp, ayp, x, y, g1, g2, out);
}

// Round 3
// 494.784 us; speedup vs baseline: 1.0732x; 1.0224x over previous
//
#include <hip/hip_runtime.h>
#include <hip/hip_bf16.h>
#include <stdint.h>

// CoAttention: B=64, C=1024, H=W=16 (N=256), CK=128.
#define B_  64
#define C_  1024
#define CK_ 128
#define N_  256

typedef __bf16 bf16;
typedef __attribute__((ext_vector_type(8))) __bf16 bf16x8;
typedef __attribute__((ext_vector_type(4))) __bf16 bf16x4;
typedef __attribute__((ext_vector_type(4))) float floatx4;

// ---- workspace layout (bytes) ----
constexpr size_t OFF_XBT = 0;                 // bf16 [64][256][1024]
constexpr size_t OFF_YBT = 33554432;
constexpr size_t OFF_WK1 = 67108864;          // bf16 [128][1024]
constexpr size_t OFF_WK2 = 67371008;
constexpr size_t OFF_WV1 = 67633152;          // bf16 [1024][1024]
constexpr size_t OFF_WV2 = 69730304;
constexpr size_t OFF_AX  = 71827456;          // bf16 [64][256][256]
constexpr size_t OFF_AY  = 80216064;
constexpr size_t WS_NEEDED = 88604672;
// kxT/kyT (bf16 [64][256][128], 4 MiB each) live in the dead out_y region:
// written by k_projk, read by k_esoft, then overwritten by k_vapply's out_y.

__device__ __forceinline__ void async16(const void* g, void* l) {
  __builtin_amdgcn_global_load_lds((const __attribute__((address_space(1))) void*)g,
                                   (__attribute__((address_space(3))) void*)l, 16, 0, 0);
}

// fp32 [C][N] -> bf16 [N][C] transpose; z<64: x-tensor, else y-tensor
__global__ __launch_bounds__(256) void k_xpose(const float* __restrict__ xin,
                                               const float* __restrict__ yin,
                                               bf16* __restrict__ xo, bf16* __restrict__ yo) {
  __shared__ float tile[64][65];
  int nt = blockIdx.x, ct = blockIdx.y, z = blockIdx.z;
  int b = z & 63;
  const float* in = (z < 64) ? xin : yin;
  bf16* out = (z < 64) ? xo : yo;
  const float* src = in + (size_t)b * C_ * N_ + (size_t)ct * 64 * N_ + nt * 64;
  bf16* dst = out + (size_t)b * N_ * C_ + (size_t)nt * 64 * C_ + ct * 64;
  int c4 = (threadIdx.x & 15) * 4, r0 = threadIdx.x >> 4;
#pragma unroll
  for (int i = 0; i < 4; ++i) {
    int r = r0 + i * 16;                       // c-local row
    float4 v = *(const float4*)(src + r * N_ + c4);
    tile[r][c4 + 0] = v.x; tile[r][c4 + 1] = v.y;
    tile[r][c4 + 2] = v.z; tile[r][c4 + 3] = v.w;
  }
  __syncthreads();
#pragma unroll
  for (int i = 0; i < 4; ++i) {
    int r = r0 + i * 16;                       // n-local row
    bf16x4 o;
    o[0] = (bf16)tile[c4 + 0][r]; o[1] = (bf16)tile[c4 + 1][r];
    o[2] = (bf16)tile[c4 + 2][r]; o[3] = (bf16)tile[c4 + 3][r];
    *(bf16x4*)(dst + (size_t)r * C_ + c4) = o;
  }
}

// two fp32->bf16 conversions in one launch
__global__ __launch_bounds__(256) void k_cvt2(const float* __restrict__ inA,
                                              const float* __restrict__ inB,
                                              bf16* __restrict__ outA, bf16* __restrict__ outB,
                                              int n4each) {
  int i = blockIdx.x * 256 + threadIdx.x;
  const float* in = (i < n4each) ? inA : inB;
  bf16* out = (i < n4each) ? outA : outB;
  int j = (i < n4each) ? i : (i - n4each);
  if (i < 2 * n4each) {
    float4 v = ((const float4*)in)[j];
    bf16x4 o;
    o[0] = (bf16)v.x; o[1] = (bf16)v.y; o[2] = (bf16)v.z; o[3] = (bf16)v.w;
    ((bf16x4*)out)[j] = o;
  }
}

// 128x128 GEMM core, 3-buffer LDS pipeline, raw s_barrier + counted vmcnt
// (never drains vmcnt to 0 in steady state; prefetch depth 2).
// LDS: As[buf] @ buf*8192 (8KB each, buf=0..2), Bs[buf] @ 24576 + buf*8192.
// smem must be 48KB. One barrier per k-step; buffer (kt+2)%3 overwritten at
// step kt was last read at step kt-1, protected by step-kt barrier.
template <int KITERS>
__device__ __forceinline__ void gemm128_core(const bf16* __restrict__ Ag, int ldA,
                                             const bf16* __restrict__ Bg, int ldB,
                                             char* smem, floatx4 (&acc)[4][4]) {
  const int tid = threadIdx.x;
  const int l = tid & 63, wid = tid >> 6;
  const int wm = wid & 1, wn = wid >> 1;
  auto issue = [&](int kt, int buf) {
    const int k0 = kt * 32;
#pragma unroll
    for (int s = 0; s < 2; ++s) {
      int row = (s << 6) + (wid << 4) + (l >> 2);
      int q = (l & 3) ^ ((row >> 1) & 3);
      async16(Ag + (size_t)row * ldA + k0 + q * 8, smem + buf * 8192 + (s << 12) + (wid << 10));
      async16(Bg + (size_t)row * ldB + k0 + q * 8, smem + 24576 + buf * 8192 + (s << 12) + (wid << 10));
    }
  };
  auto compute = [&](int buf) {
    const char* As = smem + buf * 8192;
    const char* Bs = smem + 24576 + buf * 8192;
    bf16x8 af[4], bfr[4];
#pragma unroll
    for (int t = 0; t < 4; ++t) {
      int m = (wm << 6) + t * 16 + (l & 15);
      af[t] = *(const bf16x8*)(As + m * 64 + (((l >> 4) ^ ((m >> 1) & 3)) << 4));
      int n = (wn << 6) + t * 16 + (l & 15);
      bfr[t] = *(const bf16x8*)(Bs + n * 64 + (((l >> 4) ^ ((n >> 1) & 3)) << 4));
    }
#pragma unroll
    for (int tm = 0; tm < 4; ++tm)
#pragma unroll
      for (int tn = 0; tn < 4; ++tn)
        acc[tm][tn] = __builtin_amdgcn_mfma_f32_16x16x32_bf16(af[tm], bfr[tn], acc[tm][tn], 0, 0, 0);
  };
  issue(0, 0);
  if (KITERS > 1) issue(1, 1);
#pragma unroll
  for (int kt = 0; kt < KITERS; ++kt) {
    // own loads for step kt done; step kt+1's 4 ops stay in flight across barrier
    if (kt + 1 < KITERS) asm volatile("s_waitcnt vmcnt(4) lgkmcnt(0)" ::: "memory");
    else                 asm volatile("s_waitcnt vmcnt(0) lgkmcnt(0)" ::: "memory");
    __builtin_amdgcn_s_barrier();
    asm volatile("" ::: "memory");          // keep loads/ds_reads below the barrier
    if (kt + 2 < KITERS) issue(kt + 2, (kt + 2) % 3);
    __builtin_amdgcn_s_setprio(1);
    compute(kt % 3);
    __builtin_amdgcn_s_setprio(0);
  }
}

// kT[n][o] = sum_c xbT[n][c]*wk[o][c] + bk[o]
__global__ __launch_bounds__(256) void k_projk(
    const bf16* __restrict__ xbT, const bf16* __restrict__ ybT,
    const bf16* __restrict__ wk1b, const bf16* __restrict__ wk2b,
    const float* __restrict__ bk1, const float* __restrict__ bk2,
    bf16* __restrict__ kxT, bf16* __restrict__ kyT) {
  __shared__ __align__(16) char smem[49152];
  int mt = blockIdx.x, br = blockIdx.y, b = blockIdx.z;
  const bf16* A = (br ? ybT : xbT) + (size_t)b * N_ * C_ + (size_t)mt * 128 * C_;
  const bf16* Bt = br ? wk2b : wk1b;
  const float* bias = br ? bk2 : bk1;
  bf16* out = (br ? kyT : kxT) + (size_t)b * N_ * CK_ + (size_t)mt * 128 * CK_;
  floatx4 acc[4][4];
  floatx4 z = {0.f, 0.f, 0.f, 0.f};
#pragma unroll
  for (int i = 0; i < 4; ++i)
#pragma unroll
    for (int j = 0; j < 4; ++j) acc[i][j] = z;
  gemm128_core<32>(A, C_, Bt, C_, smem, acc);
  const int l = threadIdx.x & 63, wid = threadIdx.x >> 6;
  const int wm = wid & 1, wn = wid >> 1;
#pragma unroll
  for (int tn = 0; tn < 4; ++tn) {
    int oc = (wn << 6) + tn * 16 + (l & 15);
    float bkv = bias[oc];
#pragma unroll
    for (int tm = 0; tm < 4; ++tm)
#pragma unroll
      for (int r = 0; r < 4; ++r) {
        int row = (wm << 6) + tm * 16 + ((l >> 4) << 2) + r;
        out[row * CK_ + oc] = (bf16)(acc[tm][tn][r] + bkv);
      }
  }
}

// Fused energy+softmax, E never materialized.
// br=0: Ehat = kxT @ kyT^T (strip rh*128..), row-softmax -> ax rows
// br=1: Ehat = kyT @ kxT^T              , row-softmax -> ay rows
// (row-softmax of E^T == col-softmax of E; Ehat is bit-identical either way
//  since MFMA k-summation order is position-fixed.)
// Per wave: 32 rows, acc[2][16] frags (128 VGPR), wave-local shuffle softmax.
// No LDS, no barriers.
__global__ __launch_bounds__(256) void k_esoft(
    const bf16* __restrict__ kxT, const bf16* __restrict__ kyT,
    bf16* __restrict__ ax, bf16* __restrict__ ay) {
  int rh = blockIdx.x, br = blockIdx.y, b = blockIdx.z;
  const bf16* A  = (br ? kyT : kxT) + (size_t)b * N_ * CK_;
  const bf16* Bm = (br ? kxT : kyT) + (size_t)b * N_ * CK_;
  bf16* outp = (br ? ay : ax) + (size_t)b * N_ * N_;
  const int tid = threadIdx.x, l = tid & 63, wid = tid >> 6;
  const int m0 = rh * 128 + wid * 32;

  floatx4 acc[2][16];
  floatx4 z = {0.f, 0.f, 0.f, 0.f};
#pragma unroll
  for (int i = 0; i < 2; ++i)
#pragma unroll
    for (int j = 0; j < 16; ++j) acc[i][j] = z;

#pragma unroll
  for (int kk = 0; kk < 4; ++kk) {
    bf16x8 af[2];
    const bf16* pa = A + (size_t)(m0 + (l & 15)) * CK_ + kk * 32 + ((l >> 4) << 3);
    af[0] = *(const bf16x8*)(pa);
    af[1] = *(const bf16x8*)(pa + 16 * CK_);
#pragma unroll
    for (int h = 0; h < 2; ++h) {          // two halves of tn to cap VGPR pressure
      bf16x8 bfr[8];
#pragma unroll
      for (int t = 0; t < 8; ++t) {
        int n = (h * 8 + t) * 16 + (l & 15);
        bfr[t] = *(const bf16x8*)(Bm + (size_t)n * CK_ + kk * 32 + ((l >> 4) << 3));
      }
#pragma unroll
      for (int tm = 0; tm < 2; ++tm)
#pragma unroll
        for (int t = 0; t < 8; ++t)
          acc[tm][h * 8 + t] =
              __builtin_amdgcn_mfma_f32_16x16x32_bf16(af[tm], bfr[t], acc[tm][h * 8 + t], 0, 0, 0);
    }
  }

  // row-softmax: lane holds rows m0 + tm*16 + (l>>4)*4 + r, cols tn*16 + (l&15);
  // a row lives in the 16-lane group sharing (l>>4) -> shuffle-xor 8,4,2,1.
#pragma unroll
  for (int tm = 0; tm < 2; ++tm)
#pragma unroll
    for (int r = 0; r < 4; ++r) {
      float mx = -1e30f;
#pragma unroll
      for (int tn = 0; tn < 16; ++tn) mx = fmaxf(mx, acc[tm][tn][r]);
#pragma unroll
      for (int off = 8; off > 0; off >>= 1) mx = fmaxf(mx, __shfl_xor(mx, off));
      float s = 0.f;
#pragma unroll
      for (int tn = 0; tn < 16; ++tn) {
        float e = __expf(acc[tm][tn][r] - mx);
        acc[tm][tn][r] = e;
        s += e;
      }
#pragma unroll
      for (int off = 8; off > 0; off >>= 1) s += __shfl_xor(s, off);
      float rc = 1.0f / s;
      int m = m0 + tm * 16 + ((l >> 4) << 2) + r;
#pragma unroll
      for (int tn = 0; tn < 16; ++tn)
        outp[(size_t)m * N_ + tn * 16 + (l & 15)] = (bf16)(acc[tm][tn][r] * rc);
    }
}

// Fused V: v = wv@x + bv (K=1024, B-stream 3-buf LDS pipeline + A reg-prefetch,
// raw barriers + counted vmcnt), o = v @ attn^T (K=256, reg-prefetch, no barriers),
// out = gamma*o + x.
// LDS 48KB: GEMM1 Bs[buf] @ buf*16384 (buf=0..2); GEMM2 vt@0 (overlays b0/b1 after barrier).
__global__ __launch_bounds__(256, 3) void k_vapply(
    const bf16* __restrict__ xbT, const bf16* __restrict__ ybT,
    const bf16* __restrict__ wv1b, const bf16* __restrict__ wv2b,
    const float* __restrict__ bv1, const float* __restrict__ bv2,
    const bf16* __restrict__ ax, const bf16* __restrict__ ay,
    const float* __restrict__ xin0, const float* __restrict__ yin0,
    const float* __restrict__ g1, const float* __restrict__ g2,
    float* __restrict__ out) {
  __shared__ __align__(16) char smem[49152];
  // XCD-swizzled decode: all 32 blocks of a given b land on one XCD (id%8 heuristic)
  int id = blockIdx.x;
  int xcd = id & 7;
  int idx = id >> 3;                 // 0..255
  int b = xcd + ((idx >> 5) << 3);   // 0..63
  int inner = idx & 31;
  int ct = inner & 15, br = inner >> 4;

  const bf16* A1 = (br ? wv2b : wv1b) + (size_t)ct * 64 * C_;
  const bf16* Bt1 = (br ? ybT : xbT) + (size_t)b * N_ * C_;
  const float* bias = br ? bv2 : bv1;
  const bf16* attn = (br ? ay : ax) + (size_t)b * N_ * N_;
  const float* xin = (br ? yin0 : xin0) + (size_t)b * C_ * N_ + (size_t)ct * 64 * N_;
  float gamma = br ? g2[0] : g1[0];
  float* o = out + (size_t)br * B_ * C_ * N_ + (size_t)b * C_ * N_ + (size_t)ct * 64 * N_;
  const int tid = threadIdx.x, l = tid & 63, wid = tid >> 6;

  auto loadA = [&](int kt, bf16x8 (&af)[4]) {
    const bf16* p = A1 + (size_t)(l & 15) * C_ + kt * 32 + ((l >> 4) << 3);
#pragma unroll
    for (int t = 0; t < 4; ++t) af[t] = *(const bf16x8*)(p + (size_t)t * 16 * C_);
  };
  auto issueB = [&](int kt, int buf) {
    const int k0 = kt * 32;
#pragma unroll
    for (int s = 0; s < 4; ++s) {
      int row = (s << 6) + (wid << 4) + (l >> 2);
      int q = (l & 3) ^ ((row >> 1) & 3);
      async16(Bt1 + (size_t)row * C_ + k0 + q * 8, smem + buf * 16384 + (s << 12) + (wid << 10));
    }
  };
  floatx4 acc[4][4];
  floatx4 z = {0.f, 0.f, 0.f, 0.f};
#pragma unroll
  for (int i = 0; i < 4; ++i)
#pragma unroll
    for (int j = 0; j < 4; ++j) acc[i][j] = z;

  auto compute1 = [&](int buf, bf16x8 (&af)[4]) {
    const char* Bs = smem + buf * 16384;
    bf16x8 bfr[4];
#pragma unroll
    for (int t = 0; t < 4; ++t) {
      int n = (wid << 6) + t * 16 + (l & 15);
      bfr[t] = *(const bf16x8*)(Bs + n * 64 + (((l >> 4) ^ ((n >> 1) & 3)) << 4));
    }
#pragma unroll
    for (int tm = 0; tm < 4; ++tm)
#pragma unroll
      for (int tn = 0; tn < 4; ++tn)
        acc[tm][tn] = __builtin_amdgcn_mfma_f32_16x16x32_bf16(af[tm], bfr[tn], acc[tm][tn], 0, 0, 0);
  };

  // ---- GEMM1: v[64][256] over K=1024. 3 LDS buffers, prefetch depth 2,
  // raw s_barrier + vmcnt(8) (8 VMEM ops/step: 4 global_load_lds + 4 A-reg loads).
  bf16x8 afA[4], afB[4], afC[4];
  issueB(0, 0); loadA(0, afA);
  issueB(1, 1); loadA(1, afB);
  auto step = [&](int kt, int buf, bf16x8 (&afU)[4], bf16x8 (&afN)[4], bool more1, bool more2) {
    if (more1) asm volatile("s_waitcnt vmcnt(8) lgkmcnt(0)" ::: "memory");
    else       asm volatile("s_waitcnt vmcnt(0) lgkmcnt(0)" ::: "memory");
    __builtin_amdgcn_s_barrier();
    asm volatile("" ::: "memory");        // keep loads/ds_reads below the barrier
    if (more2) { issueB(kt + 2, (buf + 2) % 3); loadA(kt + 2, afN); }
    __builtin_amdgcn_s_setprio(1);
    compute1(buf, afU);
    __builtin_amdgcn_s_setprio(0);
  };
  for (int kt = 0; kt < 30; kt += 3) {
    step(kt,     0, afA, afC, true, true);
    step(kt + 1, 1, afB, afA, true, true);
    step(kt + 2, 2, afC, afB, true, true);
  }
  step(30, 0, afA, afC, true, false);
  step(31, 1, afB, afA, false, false);
  __syncthreads();   // all Bs reads done; smem region becomes vt

  // ---- v += bias, cast bf16, swizzled into vt ----
  char* vt = smem;
#pragma unroll
  for (int tm = 0; tm < 4; ++tm)
#pragma unroll
    for (int r = 0; r < 4; ++r) {
      int rr = tm * 16 + ((l >> 4) << 2) + r;             // c-local 0..63
      float bkv = bias[ct * 64 + rr];
#pragma unroll
      for (int tn = 0; tn < 4; ++tn) {
        int n = (wid << 6) + tn * 16 + (l & 15);
        int ch = (n >> 3) ^ (rr & 7);
        *(bf16*)(vt + rr * 512 + ch * 16 + ((n & 7) << 1)) = (bf16)(acc[tm][tn][r] + bkv);
      }
    }

  auto loadB2 = [&](int kt, bf16x8 (&bb)[4]) {
    const bf16* p = attn + (size_t)((wid << 6) + (l & 15)) * N_ + kt * 32 + ((l >> 4) << 3);
#pragma unroll
    for (int t = 0; t < 4; ++t) bb[t] = *(const bf16x8*)(p + (size_t)t * 16 * N_);
  };
  auto compute2 = [&](int kt, bf16x8 (&bb)[4]) {
    bf16x8 af[4];
#pragma unroll
    for (int t = 0; t < 4; ++t) {
      int m = t * 16 + (l & 15);
      int ch = ((kt << 2) + (l >> 4)) ^ (m & 7);
      af[t] = *(const bf16x8*)(vt + m * 512 + (ch << 4));
    }
#pragma unroll
    for (int tm = 0; tm < 4; ++tm)
#pragma unroll
      for (int tn = 0; tn < 4; ++tn)
        acc[tm][tn] = __builtin_amdgcn_mfma_f32_16x16x32_bf16(af[tm], bb[tn], acc[tm][tn], 0, 0, 0);
  };

  // ---- GEMM2: o[64][256] = vt @ attn^T over K=256, reg-prefetch, no barriers ----
  bf16x8 bfA[4], bfB[4];
  loadB2(0, bfA);          // issued before barrier; drained by it
  __syncthreads();         // vt visible
#pragma unroll
  for (int i = 0; i < 4; ++i)
#pragma unroll
    for (int j = 0; j < 4; ++j) acc[i][j] = z;
  for (int kt = 0; kt < 8; kt += 2) {
    loadB2(kt + 1, bfB);
    compute2(kt, bfA);
    if (kt + 2 < 8) loadB2(kt + 2, bfA);
    compute2(kt + 1, bfB);
  }

  // ---- epilogue: out = gamma*o + x ----
#pragma unroll
  for (int tm = 0; tm < 4; ++tm)
#pragma unroll
    for (int tn = 0; tn < 4; ++tn)
#pragma unroll
      for (int r = 0; r < 4; ++r) {
        int rr = tm * 16 + ((l >> 4) << 2) + r;
        int m = (wid << 6) + tn * 16 + (l & 15);
        int idx2 = rr * N_ + m;
        o[idx2] = gamma * acc[tm][tn][r] + xin[idx2];
      }
}

__global__ __launch_bounds__(256) void k_fallback(const float4* __restrict__ x,
                                                  const float4* __restrict__ y,
                                                  float4* __restrict__ out) {
  size_t i = (size_t)blockIdx.x * 256 + threadIdx.x;
  out[i] = x[i];
  out[4194304 + i] = y[i];
}

extern "C" void kernel_launch(void* const* d_in, const int* in_sizes, int n_in,
                              void* d_out, int out_size, void* d_ws, size_t ws_size,
                              hipStream_t stream) {
  const float* x   = (const float*)d_in[0];
  const float* y   = (const float*)d_in[1];
  const float* wk1 = (const float*)d_in[2];
  const float* bk1 = (const float*)d_in[3];
  const float* wk2 = (const float*)d_in[4];
  const float* bk2 = (const float*)d_in[5];
  const float* wv1 = (const float*)d_in[6];
  const float* bv1 = (const float*)d_in[7];
  const float* wv2 = (const float*)d_in[8];
  const float* bv2 = (const float*)d_in[9];
  const float* g1  = (const float*)d_in[10];
  const float* g2  = (const float*)d_in[11];
  float* out = (float*)d_out;

  if (ws_size < WS_NEEDED) {
    k_fallback<<<16384, 256, 0, stream>>>((const float4*)x, (const float4*)y, (float4*)out);
    return;
  }

  char* ws = (char*)d_ws;
  bf16* xbT  = (bf16*)(ws + OFF_XBT);
  bf16* ybT  = (bf16*)(ws + OFF_YBT);
  bf16* wk1b = (bf16*)(ws + OFF_WK1);
  bf16* wk2b = (bf16*)(ws + OFF_WK2);
  bf16* wv1b = (bf16*)(ws + OFF_WV1);
  bf16* wv2b = (bf16*)(ws + OFF_WV2);
  bf16* axp  = (bf16*)(ws + OFF_AX);
  bf16* ayp  = (bf16*)(ws + OFF_AY);
  // kxT/kyT in the dead out_y region (overwritten later by k_vapply's out_y)
  bf16* kxT = (bf16*)((char*)out + (size_t)B_ * C_ * N_ * 4);
  bf16* kyT = (bf16*)((char*)out + (size_t)B_ * C_ * N_ * 4 + 4194304);

  k_xpose<<<dim3(4, 16, 128), 256, 0, stream>>>(x, y, xbT, ybT);
  k_cvt2<<<256, 256, 0, stream>>>(wk1, wk2, wk1b, wk2b, 32768);
  k_cvt2<<<2048, 256, 0, stream>>>(wv1, wv2, wv1b, wv2b, 262144);
  k_projk<<<dim3(2, 2, 64), 256, 0, stream>>>(xbT, ybT, wk1b, wk2b, bk1, bk2, kxT, kyT);
  k_esoft<<<dim3(2, 2, 64), 256, 0, stream>>>(kxT, kyT, axp, ayp);
  k_vapply<<<2048, 256, 0, stream>>>(xbT, ybT, wv1b, wv2b, bv1, bv2,
                                     axp, ayp, x, y, g1, g2, out);
}

// Round 4
// 415.471 us; speedup vs baseline: 1.2781x; 1.1909x over previous
//
#include <hip/hip_runtime.h>
#include <hip/hip_bf16.h>
#include <stdint.h>

// CoAttention: B=64, C=1024, H=W=16 (N=256), CK=128.
#define B_  64
#define C_  1024
#define CK_ 128
#define N_  256

typedef __bf16 bf16;
typedef __attribute__((ext_vector_type(8))) __bf16 bf16x8;
typedef __attribute__((ext_vector_type(4))) __bf16 bf16x4;
typedef __attribute__((ext_vector_type(4))) float floatx4;

// ---- workspace layout (bytes) ----
constexpr size_t OFF_XBT = 0;                 // bf16 [64][256][1024]
constexpr size_t OFF_YBT = 33554432;
constexpr size_t OFF_WK1 = 67108864;          // bf16 [128][1024]
constexpr size_t OFF_WK2 = 67371008;
constexpr size_t OFF_WV1 = 67633152;          // bf16 [1024][1024]
constexpr size_t OFF_WV2 = 69730304;
constexpr size_t OFF_AX  = 71827456;          // bf16 [64][256][256]
constexpr size_t OFF_AY  = 80216064;
constexpr size_t WS_NEEDED = 88604672;
// kxT/kyT (bf16 [64][256][128], 4 MiB each) live in the dead out_y region:
// written by k_projk, read by k_esoft, then overwritten by k_vapply's out_y.

__device__ __forceinline__ void async16(const void* g, void* l) {
  __builtin_amdgcn_global_load_lds((const __attribute__((address_space(1))) void*)g,
                                   (__attribute__((address_space(3))) void*)l, 16, 0, 0);
}

// fp32 [C][N] -> bf16 [N][C] transpose; z<64: x-tensor, else y-tensor
__global__ __launch_bounds__(256) void k_xpose(const float* __restrict__ xin,
                                               const float* __restrict__ yin,
                                               bf16* __restrict__ xo, bf16* __restrict__ yo) {
  __shared__ float tile[64][65];
  int nt = blockIdx.x, ct = blockIdx.y, z = blockIdx.z;
  int b = z & 63;
  const float* in = (z < 64) ? xin : yin;
  bf16* out = (z < 64) ? xo : yo;
  const float* src = in + (size_t)b * C_ * N_ + (size_t)ct * 64 * N_ + nt * 64;
  bf16* dst = out + (size_t)b * N_ * C_ + (size_t)nt * 64 * C_ + ct * 64;
  int c4 = (threadIdx.x & 15) * 4, r0 = threadIdx.x >> 4;
#pragma unroll
  for (int i = 0; i < 4; ++i) {
    int r = r0 + i * 16;                       // c-local row
    float4 v = *(const float4*)(src + r * N_ + c4);
    tile[r][c4 + 0] = v.x; tile[r][c4 + 1] = v.y;
    tile[r][c4 + 2] = v.z; tile[r][c4 + 3] = v.w;
  }
  __syncthreads();
#pragma unroll
  for (int i = 0; i < 4; ++i) {
    int r = r0 + i * 16;                       // n-local row
    bf16x4 o;
    o[0] = (bf16)tile[c4 + 0][r]; o[1] = (bf16)tile[c4 + 1][r];
    o[2] = (bf16)tile[c4 + 2][r]; o[3] = (bf16)tile[c4 + 3][r];
    *(bf16x4*)(dst + (size_t)r * C_ + c4) = o;
  }
}

// two fp32->bf16 conversions in one launch
__global__ __launch_bounds__(256) void k_cvt2(const float* __restrict__ inA,
                                              const float* __restrict__ inB,
                                              bf16* __restrict__ outA, bf16* __restrict__ outB,
                                              int n4each) {
  int i = blockIdx.x * 256 + threadIdx.x;
  const float* in = (i < n4each) ? inA : inB;
  bf16* out = (i < n4each) ? outA : outB;
  int j = (i < n4each) ? i : (i - n4each);
  if (i < 2 * n4each) {
    float4 v = ((const float4*)in)[j];
    bf16x4 o;
    o[0] = (bf16)v.x; o[1] = (bf16)v.y; o[2] = (bf16)v.z; o[3] = (bf16)v.w;
    ((bf16x4*)out)[j] = o;
  }
}

// 128x128 GEMM core, 3-buffer LDS pipeline, raw s_barrier + counted vmcnt
// (never drains vmcnt to 0 in steady state; prefetch depth 2).
// LDS: As[buf] @ buf*8192 (8KB each, buf=0..2), Bs[buf] @ 24576 + buf*8192.
// smem must be 48KB. One barrier per k-step; buffer (kt+2)%3 overwritten at
// step kt was last read at step kt-1, protected by step-kt barrier.
template <int KITERS>
__device__ __forceinline__ void gemm128_core(const bf16* __restrict__ Ag, int ldA,
                                             const bf16* __restrict__ Bg, int ldB,
                                             char* smem, floatx4 (&acc)[4][4]) {
  const int tid = threadIdx.x;
  const int l = tid & 63, wid = tid >> 6;
  const int wm = wid & 1, wn = wid >> 1;
  auto issue = [&](int kt, int buf) {
    const int k0 = kt * 32;
#pragma unroll
    for (int s = 0; s < 2; ++s) {
      int row = (s << 6) + (wid << 4) + (l >> 2);
      int q = (l & 3) ^ ((row >> 1) & 3);
      async16(Ag + (size_t)row * ldA + k0 + q * 8, smem + buf * 8192 + (s << 12) + (wid << 10));
      async16(Bg + (size_t)row * ldB + k0 + q * 8, smem + 24576 + buf * 8192 + (s << 12) + (wid << 10));
    }
  };
  auto compute = [&](int buf) {
    const char* As = smem + buf * 8192;
    const char* Bs = smem + 24576 + buf * 8192;
    bf16x8 af[4], bfr[4];
#pragma unroll
    for (int t = 0; t < 4; ++t) {
      int m = (wm << 6) + t * 16 + (l & 15);
      af[t] = *(const bf16x8*)(As + m * 64 + (((l >> 4) ^ ((m >> 1) & 3)) << 4));
      int n = (wn << 6) + t * 16 + (l & 15);
      bfr[t] = *(const bf16x8*)(Bs + n * 64 + (((l >> 4) ^ ((n >> 1) & 3)) << 4));
    }
#pragma unroll
    for (int tm = 0; tm < 4; ++tm)
#pragma unroll
      for (int tn = 0; tn < 4; ++tn)
        acc[tm][tn] = __builtin_amdgcn_mfma_f32_16x16x32_bf16(af[tm], bfr[tn], acc[tm][tn], 0, 0, 0);
  };
  issue(0, 0);
  if (KITERS > 1) issue(1, 1);
#pragma unroll
  for (int kt = 0; kt < KITERS; ++kt) {
    // own loads for step kt done; step kt+1's 4 ops stay in flight across barrier
    if (kt + 1 < KITERS) asm volatile("s_waitcnt vmcnt(4) lgkmcnt(0)" ::: "memory");
    else                 asm volatile("s_waitcnt vmcnt(0) lgkmcnt(0)" ::: "memory");
    __builtin_amdgcn_s_barrier();
    asm volatile("" ::: "memory");          // keep loads/ds_reads below the barrier
    if (kt + 2 < KITERS) issue(kt + 2, (kt + 2) % 3);
    __builtin_amdgcn_s_setprio(1);
    compute(kt % 3);
    __builtin_amdgcn_s_setprio(0);
  }
}

// kT[n][o] = sum_c xbT[n][c]*wk[o][c] + bk[o]
__global__ __launch_bounds__(256) void k_projk(
    const bf16* __restrict__ xbT, const bf16* __restrict__ ybT,
    const bf16* __restrict__ wk1b, const bf16* __restrict__ wk2b,
    const float* __restrict__ bk1, const float* __restrict__ bk2,
    bf16* __restrict__ kxT, bf16* __restrict__ kyT) {
  __shared__ __align__(16) char smem[49152];
  int mt = blockIdx.x, br = blockIdx.y, b = blockIdx.z;
  const bf16* A = (br ? ybT : xbT) + (size_t)b * N_ * C_ + (size_t)mt * 128 * C_;
  const bf16* Bt = br ? wk2b : wk1b;
  const float* bias = br ? bk2 : bk1;
  bf16* out = (br ? kyT : kxT) + (size_t)b * N_ * CK_ + (size_t)mt * 128 * CK_;
  floatx4 acc[4][4];
  floatx4 z = {0.f, 0.f, 0.f, 0.f};
#pragma unroll
  for (int i = 0; i < 4; ++i)
#pragma unroll
    for (int j = 0; j < 4; ++j) acc[i][j] = z;
  gemm128_core<32>(A, C_, Bt, C_, smem, acc);
  const int l = threadIdx.x & 63, wid = threadIdx.x >> 6;
  const int wm = wid & 1, wn = wid >> 1;
#pragma unroll
  for (int tn = 0; tn < 4; ++tn) {
    int oc = (wn << 6) + tn * 16 + (l & 15);
    float bkv = bias[oc];
#pragma unroll
    for (int tm = 0; tm < 4; ++tm)
#pragma unroll
      for (int r = 0; r < 4; ++r) {
        int row = (wm << 6) + tm * 16 + ((l >> 4) << 2) + r;
        out[row * CK_ + oc] = (bf16)(acc[tm][tn][r] + bkv);
      }
  }
}

// Fused energy+softmax, E never materialized.
// br=0: Ehat = kxT @ kyT^T (strip rh*128..), row-softmax -> ax rows
// br=1: Ehat = kyT @ kxT^T              , row-softmax -> ay rows
__global__ __launch_bounds__(256) void k_esoft(
    const bf16* __restrict__ kxT, const bf16* __restrict__ kyT,
    bf16* __restrict__ ax, bf16* __restrict__ ay) {
  int rh = blockIdx.x, br = blockIdx.y, b = blockIdx.z;
  const bf16* A  = (br ? kyT : kxT) + (size_t)b * N_ * CK_;
  const bf16* Bm = (br ? kxT : kyT) + (size_t)b * N_ * CK_;
  bf16* outp = (br ? ay : ax) + (size_t)b * N_ * N_;
  const int tid = threadIdx.x, l = tid & 63, wid = tid >> 6;
  const int m0 = rh * 128 + wid * 32;

  floatx4 acc[2][16];
  floatx4 z = {0.f, 0.f, 0.f, 0.f};
#pragma unroll
  for (int i = 0; i < 2; ++i)
#pragma unroll
    for (int j = 0; j < 16; ++j) acc[i][j] = z;

#pragma unroll
  for (int kk = 0; kk < 4; ++kk) {
    bf16x8 af[2];
    const bf16* pa = A + (size_t)(m0 + (l & 15)) * CK_ + kk * 32 + ((l >> 4) << 3);
    af[0] = *(const bf16x8*)(pa);
    af[1] = *(const bf16x8*)(pa + 16 * CK_);
#pragma unroll
    for (int h = 0; h < 2; ++h) {          // two halves of tn to cap VGPR pressure
      bf16x8 bfr[8];
#pragma unroll
      for (int t = 0; t < 8; ++t) {
        int n = (h * 8 + t) * 16 + (l & 15);
        bfr[t] = *(const bf16x8*)(Bm + (size_t)n * CK_ + kk * 32 + ((l >> 4) << 3));
      }
#pragma unroll
      for (int tm = 0; tm < 2; ++tm)
#pragma unroll
        for (int t = 0; t < 8; ++t)
          acc[tm][h * 8 + t] =
              __builtin_amdgcn_mfma_f32_16x16x32_bf16(af[tm], bfr[t], acc[tm][h * 8 + t], 0, 0, 0);
    }
  }

  // row-softmax: lane holds rows m0 + tm*16 + (l>>4)*4 + r, cols tn*16 + (l&15);
  // a row lives in the 16-lane group sharing (l>>4) -> shuffle-xor 8,4,2,1.
#pragma unroll
  for (int tm = 0; tm < 2; ++tm)
#pragma unroll
    for (int r = 0; r < 4; ++r) {
      float mx = -1e30f;
#pragma unroll
      for (int tn = 0; tn < 16; ++tn) mx = fmaxf(mx, acc[tm][tn][r]);
#pragma unroll
      for (int off = 8; off > 0; off >>= 1) mx = fmaxf(mx, __shfl_xor(mx, off));
      float s = 0.f;
#pragma unroll
      for (int tn = 0; tn < 16; ++tn) {
        float e = __expf(acc[tm][tn][r] - mx);
        acc[tm][tn][r] = e;
        s += e;
      }
#pragma unroll
      for (int off = 8; off > 0; off >>= 1) s += __shfl_xor(s, off);
      float rc = 1.0f / s;
      int m = m0 + tm * 16 + ((l >> 4) << 2) + r;
#pragma unroll
      for (int tn = 0; tn < 16; ++tn)
        outp[(size_t)m * N_ + tn * 16 + (l & 15)] = (bf16)(acc[tm][tn][r] * rc);
    }
}

// Fused V, 512 threads, 128c x 256n tile per block (1024 blocks).
// GEMM1: v = wv@x + bv over K=1024. A (wv 128x32/step) AND B (xbT 256x32/step)
// staged via global_load_lds: A 2 bufs depth-1, B 3 bufs depth-2.
// Per-step VMEM/thread = 3 (A,B,B in that order) -> steady wait vmcnt(2):
// retires this step's A+B, leaves next B pair in flight across the barrier.
// GEMM2: o = v @ attn^T over K=256, vt (128x256 bf16, 64KB) overlays all bufs.
// LDS 64KB exact: Abuf[2]@0 (8KB ea), Bbuf[3]@16384 (16KB ea); vt@0 after GEMM1.
// 8 waves as 2(m) x 4(n); 2 blocks/CU (128KB LDS/CU), grid = 2 full waves.
__global__ __launch_bounds__(512, 4) void k_vapply(
    const bf16* __restrict__ xbT, const bf16* __restrict__ ybT,
    const bf16* __restrict__ wv1b, const bf16* __restrict__ wv2b,
    const float* __restrict__ bv1, const float* __restrict__ bv2,
    const bf16* __restrict__ ax, const bf16* __restrict__ ay,
    const float* __restrict__ xin0, const float* __restrict__ yin0,
    const float* __restrict__ g1, const float* __restrict__ g2,
    float* __restrict__ out) {
  __shared__ __align__(16) char smem[65536];
  // XCD-swizzled decode: all 16 blocks of a given b land on one XCD
  int id = blockIdx.x;
  int xcd = id & 7;
  int idx = id >> 3;                 // 0..127
  int b = xcd + ((idx >> 4) << 3);   // 0..63
  int inner = idx & 15;
  int ct = inner & 7, br = inner >> 3;

  const bf16* A1 = (br ? wv2b : wv1b) + (size_t)ct * 128 * C_;
  const bf16* Bt1 = (br ? ybT : xbT) + (size_t)b * N_ * C_;
  const float* bias = br ? bv2 : bv1;
  const bf16* attn = (br ? ay : ax) + (size_t)b * N_ * N_;
  const float* xin = (br ? yin0 : xin0) + (size_t)b * C_ * N_ + (size_t)ct * 128 * N_;
  float gamma = br ? g2[0] : g1[0];
  float* o = out + (size_t)br * B_ * C_ * N_ + (size_t)b * C_ * N_ + (size_t)ct * 128 * N_;
  const int tid = threadIdx.x, l = tid & 63, wid = tid >> 6;
  const int wm = wid >> 2, wn = wid & 3;

  auto issueA = [&](int kt, int abuf) {
    int row = (wid << 4) + (l >> 2);                     // 0..127 (c-local)
    int q = (l & 3) ^ ((row >> 1) & 3);
    async16(A1 + (size_t)row * C_ + kt * 32 + q * 8, smem + abuf * 8192 + (wid << 10));
  };
  auto issueB = [&](int kt, int bbuf) {
#pragma unroll
    for (int s = 0; s < 2; ++s) {
      int row = (s << 7) + (wid << 4) + (l >> 2);        // 0..255 (n-local)
      int q = (l & 3) ^ ((row >> 1) & 3);
      async16(Bt1 + (size_t)row * C_ + kt * 32 + q * 8,
              smem + 16384 + bbuf * 16384 + (s << 13) + (wid << 10));
    }
  };
  floatx4 acc[4][4];
  floatx4 z = {0.f, 0.f, 0.f, 0.f};
#pragma unroll
  for (int i = 0; i < 4; ++i)
#pragma unroll
    for (int j = 0; j < 4; ++j) acc[i][j] = z;

  auto compute1 = [&](int abuf, int bbuf) {
    const char* As = smem + abuf * 8192;
    const char* Bs = smem + 16384 + bbuf * 16384;
    bf16x8 af[4], bfr[4];
#pragma unroll
    for (int t = 0; t < 4; ++t) {
      int m = (wm << 6) + t * 16 + (l & 15);
      af[t] = *(const bf16x8*)(As + m * 64 + (((l >> 4) ^ ((m >> 1) & 3)) << 4));
      int n = (wn << 6) + t * 16 + (l & 15);
      bfr[t] = *(const bf16x8*)(Bs + n * 64 + (((l >> 4) ^ ((n >> 1) & 3)) << 4));
    }
#pragma unroll
    for (int tm = 0; tm < 4; ++tm)
#pragma unroll
      for (int tn = 0; tn < 4; ++tn)
        acc[tm][tn] = __builtin_amdgcn_mfma_f32_16x16x32_bf16(af[tm], bfr[tn], acc[tm][tn], 0, 0, 0);
  };

  // ---- GEMM1 pipeline. Hazards: abuf (kt+1)&1 / bbuf (kt+2)%3 written at step
  // kt were last ds_read at step kt-1; lgkmcnt(0)+barrier at step kt protect.
  issueA(0, 0); issueB(0, 0); issueB(1, 1);
#pragma unroll
  for (int kt = 0; kt < 32; ++kt) {
    if (kt < 31) asm volatile("s_waitcnt vmcnt(2) lgkmcnt(0)" ::: "memory");
    else         asm volatile("s_waitcnt vmcnt(0) lgkmcnt(0)" ::: "memory");
    __builtin_amdgcn_s_barrier();
    asm volatile("" ::: "memory");        // keep loads/ds_reads below the barrier
    if (kt < 31) issueA(kt + 1, (kt + 1) & 1);
    if (kt < 30) issueB(kt + 2, (kt + 2) % 3);
    __builtin_amdgcn_s_setprio(1);
    compute1(kt & 1, kt % 3);
    __builtin_amdgcn_s_setprio(0);
  }
  __syncthreads();   // all buf reads done; smem region becomes vt

  // ---- v += bias, cast bf16, swizzled into vt (128 rows x 512B) ----
  char* vt = smem;
#pragma unroll
  for (int tm = 0; tm < 4; ++tm)
#pragma unroll
    for (int r = 0; r < 4; ++r) {
      int rr = (wm << 6) + tm * 16 + ((l >> 4) << 2) + r;   // c-local 0..127
      float bkv = bias[ct * 128 + rr];
#pragma unroll
      for (int tn = 0; tn < 4; ++tn) {
        int n = (wn << 6) + tn * 16 + (l & 15);
        int ch = (n >> 3) ^ (rr & 7);
        *(bf16*)(vt + rr * 512 + ch * 16 + ((n & 7) << 1)) = (bf16)(acc[tm][tn][r] + bkv);
      }
    }

  auto loadB2 = [&](int kt, bf16x8 (&bb)[4]) {
    const bf16* p = attn + (size_t)((wn << 6) + (l & 15)) * N_ + kt * 32 + ((l >> 4) << 3);
#pragma unroll
    for (int t = 0; t < 4; ++t) bb[t] = *(const bf16x8*)(p + (size_t)t * 16 * N_);
  };
  auto compute2 = [&](int kt, bf16x8 (&bb)[4]) {
    bf16x8 af[4];
#pragma unroll
    for (int t = 0; t < 4; ++t) {
      int m = (wm << 6) + t * 16 + (l & 15);
      int ch = ((kt << 2) + (l >> 4)) ^ (m & 7);
      af[t] = *(const bf16x8*)(vt + m * 512 + (ch << 4));
    }
#pragma unroll
    for (int tm = 0; tm < 4; ++tm)
#pragma unroll
      for (int tn = 0; tn < 4; ++tn)
        acc[tm][tn] = __builtin_amdgcn_mfma_f32_16x16x32_bf16(af[tm], bb[tn], acc[tm][tn], 0, 0, 0);
  };

  // ---- GEMM2: o[128][256] = vt @ attn^T over K=256, reg-prefetch, no barriers ----
  bf16x8 bfA[4], bfB[4];
  loadB2(0, bfA);          // issued before barrier; drained by it
  __syncthreads();         // vt visible
#pragma unroll
  for (int i = 0; i < 4; ++i)
#pragma unroll
    for (int j = 0; j < 4; ++j) acc[i][j] = z;
  for (int kt = 0; kt < 8; kt += 2) {
    loadB2(kt + 1, bfB);
    compute2(kt, bfA);
    if (kt + 2 < 8) loadB2(kt + 2, bfA);
    compute2(kt + 1, bfB);
  }

  // ---- epilogue: out = gamma*o + x ----
#pragma unroll
  for (int tm = 0; tm < 4; ++tm)
#pragma unroll
    for (int tn = 0; tn < 4; ++tn)
#pragma unroll
      for (int r = 0; r < 4; ++r) {
        int rr = (wm << 6) + tm * 16 + ((l >> 4) << 2) + r;
        int m = (wn << 6) + tn * 16 + (l & 15);
        int idx2 = rr * N_ + m;
        o[idx2] = gamma * acc[tm][tn][r] + xin[idx2];
      }
}

__global__ __launch_bounds__(256) void k_fallback(const float4* __restrict__ x,
                                                  const float4* __restrict__ y,
                                                  float4* __restrict__ out) {
  size_t i = (size_t)blockIdx.x * 256 + threadIdx.x;
  out[i] = x[i];
  out[4194304 + i] = y[i];
}

extern "C" void kernel_launch(void* const* d_in, const int* in_sizes, int n_in,
                              void* d_out, int out_size, void* d_ws, size_t ws_size,
                              hipStream_t stream) {
  const float* x   = (const float*)d_in[0];
  const float* y   = (const float*)d_in[1];
  const float* wk1 = (const float*)d_in[2];
  const float* bk1 = (const float*)d_in[3];
  const float* wk2 = (const float*)d_in[4];
  const float* bk2 = (const float*)d_in[5];
  const float* wv1 = (const float*)d_in[6];
  const float* bv1 = (const float*)d_in[7];
  const float* wv2 = (const float*)d_in[8];
  const float* bv2 = (const float*)d_in[9];
  const float* g1  = (const float*)d_in[10];
  const float* g2  = (const float*)d_in[11];
  float* out = (float*)d_out;

  if (ws_size < WS_NEEDED) {
    k_fallback<<<16384, 256, 0, stream>>>((const float4*)x, (const float4*)y, (float4*)out);
    return;
  }

  char* ws = (char*)d_ws;
  bf16* xbT  = (bf16*)(ws + OFF_XBT);
  bf16* ybT  = (bf16*)(ws + OFF_YBT);
  bf16* wk1b = (bf16*)(ws + OFF_WK1);
  bf16* wk2b = (bf16*)(ws + OFF_WK2);
  bf16* wv1b = (bf16*)(ws + OFF_WV1);
  bf16* wv2b = (bf16*)(ws + OFF_WV2);
  bf16* axp  = (bf16*)(ws + OFF_AX);
  bf16* ayp  = (bf16*)(ws + OFF_AY);
  // kxT/kyT in the dead out_y region (overwritten later by k_vapply's out_y)
  bf16* kxT = (bf16*)((char*)out + (size_t)B_ * C_ * N_ * 4);
  bf16* kyT = (bf16*)((char*)out + (size_t)B_ * C_ * N_ * 4 + 4194304);

  k_xpose<<<dim3(4, 16, 128), 256, 0, stream>>>(x, y, xbT, ybT);
  k_cvt2<<<256, 256, 0, stream>>>(wk1, wk2, wk1b, wk2b, 32768);
  k_cvt2<<<2048, 256, 0, stream>>>(wv1, wv2, wv1b, wv2b, 262144);
  k_projk<<<dim3(2, 2, 64), 256, 0, stream>>>(xbT, ybT, wk1b, wk2b, bk1, bk2, kxT, kyT);
  k_esoft<<<dim3(2, 2, 64), 256, 0, stream>>>(kxT, kyT, axp, ayp);
  k_vapply<<<1024, 512, 0, stream>>>(xbT, ybT, wv1b, wv2b, bv1, bv2,
                                     axp, ayp, x, y, g1, g2, out);
}

// Round 5
// 402.319 us; speedup vs baseline: 1.3199x; 1.0327x over previous
//
#include <hip/hip_runtime.h>
#include <hip/hip_bf16.h>
#include <stdint.h>

// CoAttention: B=64, C=1024, H=W=16 (N=256), CK=128.
#define B_  64
#define C_  1024
#define CK_ 128
#define N_  256

typedef __bf16 bf16;
typedef __attribute__((ext_vector_type(8))) __bf16 bf16x8;
typedef __attribute__((ext_vector_type(4))) __bf16 bf16x4;
typedef __attribute__((ext_vector_type(4))) float floatx4;

// ---- workspace layout (bytes) ----
constexpr size_t OFF_XBT = 0;                 // bf16 [64][256][1024]
constexpr size_t OFF_YBT = 33554432;
constexpr size_t OFF_WK1 = 67108864;          // bf16 [128][1024]
constexpr size_t OFF_WK2 = 67371008;
constexpr size_t OFF_WV1 = 67633152;          // bf16 [1024][1024]
constexpr size_t OFF_WV2 = 69730304;
constexpr size_t OFF_AX  = 71827456;          // bf16 [64][256][256]
constexpr size_t OFF_AY  = 80216064;
constexpr size_t WS_NEEDED = 88604672;
// kxT/kyT (bf16 [64][256][128], 4 MiB each) live in the dead out_y region:
// written by k_projk, read by k_esoft, then overwritten by k_vapply's out_y.

__device__ __forceinline__ void async16(const void* g, void* l) {
  __builtin_amdgcn_global_load_lds((const __attribute__((address_space(1))) void*)g,
                                   (__attribute__((address_space(3))) void*)l, 16, 0, 0);
}

// fp32 [C][N] -> bf16 [N][C] transpose; z<64: x-tensor, else y-tensor
__global__ __launch_bounds__(256) void k_xpose(const float* __restrict__ xin,
                                               const float* __restrict__ yin,
                                               bf16* __restrict__ xo, bf16* __restrict__ yo) {
  __shared__ float tile[64][65];
  int nt = blockIdx.x, ct = blockIdx.y, z = blockIdx.z;
  int b = z & 63;
  const float* in = (z < 64) ? xin : yin;
  bf16* out = (z < 64) ? xo : yo;
  const float* src = in + (size_t)b * C_ * N_ + (size_t)ct * 64 * N_ + nt * 64;
  bf16* dst = out + (size_t)b * N_ * C_ + (size_t)nt * 64 * C_ + ct * 64;
  int c4 = (threadIdx.x & 15) * 4, r0 = threadIdx.x >> 4;
#pragma unroll
  for (int i = 0; i < 4; ++i) {
    int r = r0 + i * 16;                       // c-local row
    float4 v = *(const float4*)(src + r * N_ + c4);
    tile[r][c4 + 0] = v.x; tile[r][c4 + 1] = v.y;
    tile[r][c4 + 2] = v.z; tile[r][c4 + 3] = v.w;
  }
  __syncthreads();
#pragma unroll
  for (int i = 0; i < 4; ++i) {
    int r = r0 + i * 16;                       // n-local row
    bf16x4 o;
    o[0] = (bf16)tile[c4 + 0][r]; o[1] = (bf16)tile[c4 + 1][r];
    o[2] = (bf16)tile[c4 + 2][r]; o[3] = (bf16)tile[c4 + 3][r];
    *(bf16x4*)(dst + (size_t)r * C_ + c4) = o;
  }
}

// all four fp32->bf16 weight conversions in ONE launch.
// grid must be exactly (2*32768 + 2*262144)/256 = 2304 blocks.
__global__ __launch_bounds__(256) void k_cvt4(
    const float* __restrict__ wk1, const float* __restrict__ wk2,
    bf16* __restrict__ ok1, bf16* __restrict__ ok2,
    const float* __restrict__ wv1, const float* __restrict__ wv2,
    bf16* __restrict__ ov1, bf16* __restrict__ ov2) {
  int i = blockIdx.x * 256 + threadIdx.x;
  const float* in; bf16* out; int j;
  if (i < 65536) {
    bool s = i < 32768;
    in = s ? wk1 : wk2; out = s ? ok1 : ok2; j = s ? i : i - 32768;
  } else {
    int k = i - 65536;
    bool s = k < 262144;
    in = s ? wv1 : wv2; out = s ? ov1 : ov2; j = s ? k : k - 262144;
  }
  float4 v = ((const float4*)in)[j];
  bf16x4 o;
  o[0] = (bf16)v.x; o[1] = (bf16)v.y; o[2] = (bf16)v.z; o[3] = (bf16)v.w;
  ((bf16x4*)out)[j] = o;
}

// 128x128 GEMM core, 3-buffer LDS pipeline, raw s_barrier + counted vmcnt
// (never drains vmcnt to 0 in steady state; prefetch depth 2).
// LDS: As[buf] @ buf*8192 (8KB each, buf=0..2), Bs[buf] @ 24576 + buf*8192.
// smem must be 48KB. One barrier per k-step; buffer (kt+2)%3 overwritten at
// step kt was last read at step kt-1, protected by step-kt barrier.
template <int KITERS>
__device__ __forceinline__ void gemm128_core(const bf16* __restrict__ Ag, int ldA,
                                             const bf16* __restrict__ Bg, int ldB,
                                             char* smem, floatx4 (&acc)[4][4]) {
  const int tid = threadIdx.x;
  const int l = tid & 63, wid = tid >> 6;
  const int wm = wid & 1, wn = wid >> 1;
  auto issue = [&](int kt, int buf) {
    const int k0 = kt * 32;
#pragma unroll
    for (int s = 0; s < 2; ++s) {
      int row = (s << 6) + (wid << 4) + (l >> 2);
      int q = (l & 3) ^ ((row >> 1) & 3);
      async16(Ag + (size_t)row * ldA + k0 + q * 8, smem + buf * 8192 + (s << 12) + (wid << 10));
      async16(Bg + (size_t)row * ldB + k0 + q * 8, smem + 24576 + buf * 8192 + (s << 12) + (wid << 10));
    }
  };
  auto compute = [&](int buf) {
    const char* As = smem + buf * 8192;
    const char* Bs = smem + 24576 + buf * 8192;
    bf16x8 af[4], bfr[4];
#pragma unroll
    for (int t = 0; t < 4; ++t) {
      int m = (wm << 6) + t * 16 + (l & 15);
      af[t] = *(const bf16x8*)(As + m * 64 + (((l >> 4) ^ ((m >> 1) & 3)) << 4));
      int n = (wn << 6) + t * 16 + (l & 15);
      bfr[t] = *(const bf16x8*)(Bs + n * 64 + (((l >> 4) ^ ((n >> 1) & 3)) << 4));
    }
#pragma unroll
    for (int tm = 0; tm < 4; ++tm)
#pragma unroll
      for (int tn = 0; tn < 4; ++tn)
        acc[tm][tn] = __builtin_amdgcn_mfma_f32_16x16x32_bf16(af[tm], bfr[tn], acc[tm][tn], 0, 0, 0);
  };
  issue(0, 0);
  if (KITERS > 1) issue(1, 1);
#pragma unroll
  for (int kt = 0; kt < KITERS; ++kt) {
    // own loads for step kt done; step kt+1's 4 ops stay in flight across barrier
    if (kt + 1 < KITERS) asm volatile("s_waitcnt vmcnt(4) lgkmcnt(0)" ::: "memory");
    else                 asm volatile("s_waitcnt vmcnt(0) lgkmcnt(0)" ::: "memory");
    __builtin_amdgcn_s_barrier();
    asm volatile("" ::: "memory");          // keep loads/ds_reads below the barrier
    if (kt + 2 < KITERS) issue(kt + 2, (kt + 2) % 3);
    __builtin_amdgcn_s_setprio(1);
    compute(kt % 3);
    __builtin_amdgcn_s_setprio(0);
  }
}

// kT[n][o] = sum_c xbT[n][c]*wk[o][c] + bk[o]
__global__ __launch_bounds__(256) void k_projk(
    const bf16* __restrict__ xbT, const bf16* __restrict__ ybT,
    const bf16* __restrict__ wk1b, const bf16* __restrict__ wk2b,
    const float* __restrict__ bk1, const float* __restrict__ bk2,
    bf16* __restrict__ kxT, bf16* __restrict__ kyT) {
  __shared__ __align__(16) char smem[49152];
  int mt = blockIdx.x, br = blockIdx.y, b = blockIdx.z;
  const bf16* A = (br ? ybT : xbT) + (size_t)b * N_ * C_ + (size_t)mt * 128 * C_;
  const bf16* Bt = br ? wk2b : wk1b;
  const float* bias = br ? bk2 : bk1;
  bf16* out = (br ? kyT : kxT) + (size_t)b * N_ * CK_ + (size_t)mt * 128 * CK_;
  floatx4 acc[4][4];
  floatx4 z = {0.f, 0.f, 0.f, 0.f};
#pragma unroll
  for (int i = 0; i < 4; ++i)
#pragma unroll
    for (int j = 0; j < 4; ++j) acc[i][j] = z;
  gemm128_core<32>(A, C_, Bt, C_, smem, acc);
  const int l = threadIdx.x & 63, wid = threadIdx.x >> 6;
  const int wm = wid & 1, wn = wid >> 1;
#pragma unroll
  for (int tn = 0; tn < 4; ++tn) {
    int oc = (wn << 6) + tn * 16 + (l & 15);
    float bkv = bias[oc];
#pragma unroll
    for (int tm = 0; tm < 4; ++tm)
#pragma unroll
      for (int r = 0; r < 4; ++r) {
        int row = (wm << 6) + tm * 16 + ((l >> 4) << 2) + r;
        out[row * CK_ + oc] = (bf16)(acc[tm][tn][r] + bkv);
      }
  }
}

// Fused energy+softmax, E never materialized.
// br=0: Ehat = kxT @ kyT^T (strip rh*128..), row-softmax -> ax rows
// br=1: Ehat = kyT @ kxT^T              , row-softmax -> ay rows
__global__ __launch_bounds__(256) void k_esoft(
    const bf16* __restrict__ kxT, const bf16* __restrict__ kyT,
    bf16* __restrict__ ax, bf16* __restrict__ ay) {
  int rh = blockIdx.x, br = blockIdx.y, b = blockIdx.z;
  const bf16* A  = (br ? kyT : kxT) + (size_t)b * N_ * CK_;
  const bf16* Bm = (br ? kxT : kyT) + (size_t)b * N_ * CK_;
  bf16* outp = (br ? ay : ax) + (size_t)b * N_ * N_;
  const int tid = threadIdx.x, l = tid & 63, wid = tid >> 6;
  const int m0 = rh * 128 + wid * 32;

  floatx4 acc[2][16];
  floatx4 z = {0.f, 0.f, 0.f, 0.f};
#pragma unroll
  for (int i = 0; i < 2; ++i)
#pragma unroll
    for (int j = 0; j < 16; ++j) acc[i][j] = z;

#pragma unroll
  for (int kk = 0; kk < 4; ++kk) {
    bf16x8 af[2];
    const bf16* pa = A + (size_t)(m0 + (l & 15)) * CK_ + kk * 32 + ((l >> 4) << 3);
    af[0] = *(const bf16x8*)(pa);
    af[1] = *(const bf16x8*)(pa + 16 * CK_);
#pragma unroll
    for (int h = 0; h < 2; ++h) {          // two halves of tn to cap VGPR pressure
      bf16x8 bfr[8];
#pragma unroll
      for (int t = 0; t < 8; ++t) {
        int n = (h * 8 + t) * 16 + (l & 15);
        bfr[t] = *(const bf16x8*)(Bm + (size_t)n * CK_ + kk * 32 + ((l >> 4) << 3));
      }
#pragma unroll
      for (int tm = 0; tm < 2; ++tm)
#pragma unroll
        for (int t = 0; t < 8; ++t)
          acc[tm][h * 8 + t] =
              __builtin_amdgcn_mfma_f32_16x16x32_bf16(af[tm], bfr[t], acc[tm][h * 8 + t], 0, 0, 0);
    }
  }

  // row-softmax: lane holds rows m0 + tm*16 + (l>>4)*4 + r, cols tn*16 + (l&15);
  // a row lives in the 16-lane group sharing (l>>4) -> shuffle-xor 8,4,2,1.
#pragma unroll
  for (int tm = 0; tm < 2; ++tm)
#pragma unroll
    for (int r = 0; r < 4; ++r) {
      float mx = -1e30f;
#pragma unroll
      for (int tn = 0; tn < 16; ++tn) mx = fmaxf(mx, acc[tm][tn][r]);
#pragma unroll
      for (int off = 8; off > 0; off >>= 1) mx = fmaxf(mx, __shfl_xor(mx, off));
      float s = 0.f;
#pragma unroll
      for (int tn = 0; tn < 16; ++tn) {
        float e = __expf(acc[tm][tn][r] - mx);
        acc[tm][tn][r] = e;
        s += e;
      }
#pragma unroll
      for (int off = 8; off > 0; off >>= 1) s += __shfl_xor(s, off);
      float rc = 1.0f / s;
      int m = m0 + tm * 16 + ((l >> 4) << 2) + r;
#pragma unroll
      for (int tn = 0; tn < 16; ++tn)
        outp[(size_t)m * N_ + tn * 16 + (l & 15)] = (bf16)(acc[tm][tn][r] * rc);
    }
}

// Fused V, 512 threads, 256c x 256n tile per block (512 blocks, 1 block/CU).
// GEMM1: v = wv@x + bv over K=1024. A (wv 256x32/step) AND B (xbT 256x32/step)
// staged via global_load_lds: A 2 bufs depth-1, B 3 bufs depth-2.
// Per-step VMEM/thread = 4 (A,A,B,B) -> steady wait vmcnt(2): retires this
// step's A+B, leaves next B pair in flight across the barrier.
// GEMM2: o = v @ attn^T over K=256, vt (256x256 bf16, 128KB) overlays all bufs.
// LDS 128KB: Abuf[2]@0 (16KB ea), Bbuf[3]@32768 (16KB ea); vt@0 after GEMM1.
// 8 waves as 2(m: 128 rows) x 4(n: 64 cols); acc[8][4] = 128 VGPR, static idx.
__global__ __launch_bounds__(512, 2) void k_vapply(
    const bf16* __restrict__ xbT, const bf16* __restrict__ ybT,
    const bf16* __restrict__ wv1b, const bf16* __restrict__ wv2b,
    const float* __restrict__ bv1, const float* __restrict__ bv2,
    const bf16* __restrict__ ax, const bf16* __restrict__ ay,
    const float* __restrict__ xin0, const float* __restrict__ yin0,
    const float* __restrict__ g1, const float* __restrict__ g2,
    float* __restrict__ out) {
  __shared__ __align__(16) char smem[131072];
  // XCD-swizzled decode: all 8 blocks (4ct x 2br) of a given b land on one XCD
  int id = blockIdx.x;
  int xcd = id & 7;
  int idx = id >> 3;                 // 0..63
  int b = xcd + ((idx >> 3) << 3);   // 0..63
  int inner = idx & 7;
  int ct = inner & 3, br = inner >> 2;

  const bf16* A1 = (br ? wv2b : wv1b) + (size_t)ct * 256 * C_;
  const bf16* Bt1 = (br ? ybT : xbT) + (size_t)b * N_ * C_;
  const float* bias = br ? bv2 : bv1;
  const bf16* attn = (br ? ay : ax) + (size_t)b * N_ * N_;
  const float* xin = (br ? yin0 : xin0) + (size_t)b * C_ * N_ + (size_t)ct * 256 * N_;
  float gamma = br ? g2[0] : g1[0];
  float* o = out + (size_t)br * B_ * C_ * N_ + (size_t)b * C_ * N_ + (size_t)ct * 256 * N_;
  const int tid = threadIdx.x, l = tid & 63, wid = tid >> 6;
  const int wm = wid >> 2, wn = wid & 3;

  auto issueA = [&](int kt, int abuf) {
#pragma unroll
    for (int s = 0; s < 2; ++s) {
      int row = (s << 7) + (wid << 4) + (l >> 2);        // 0..255 (c-local)
      int q = (l & 3) ^ ((row >> 1) & 3);
      async16(A1 + (size_t)row * C_ + kt * 32 + q * 8,
              smem + abuf * 16384 + (s << 13) + (wid << 10));
    }
  };
  auto issueB = [&](int kt, int bbuf) {
#pragma unroll
    for (int s = 0; s < 2; ++s) {
      int row = (s << 7) + (wid << 4) + (l >> 2);        // 0..255 (n-local)
      int q = (l & 3) ^ ((row >> 1) & 3);
      async16(Bt1 + (size_t)row * C_ + kt * 32 + q * 8,
              smem + 32768 + bbuf * 16384 + (s << 13) + (wid << 10));
    }
  };
  floatx4 acc[8][4];
  floatx4 z = {0.f, 0.f, 0.f, 0.f};
#pragma unroll
  for (int i = 0; i < 8; ++i)
#pragma unroll
    for (int j = 0; j < 4; ++j) acc[i][j] = z;

  auto compute1 = [&](int abuf, int bbuf) {
    const char* As = smem + abuf * 16384;
    const char* Bs = smem + 32768 + bbuf * 16384;
    bf16x8 af[8], bfr[4];
#pragma unroll
    for (int t = 0; t < 8; ++t) {
      int m = (wm << 7) + t * 16 + (l & 15);
      af[t] = *(const bf16x8*)(As + m * 64 + (((l >> 4) ^ ((m >> 1) & 3)) << 4));
    }
#pragma unroll
    for (int t = 0; t < 4; ++t) {
      int n = (wn << 6) + t * 16 + (l & 15);
      bfr[t] = *(const bf16x8*)(Bs + n * 64 + (((l >> 4) ^ ((n >> 1) & 3)) << 4));
    }
#pragma unroll
    for (int tm = 0; tm < 8; ++tm)
#pragma unroll
      for (int tn = 0; tn < 4; ++tn)
        acc[tm][tn] = __builtin_amdgcn_mfma_f32_16x16x32_bf16(af[tm], bfr[tn], acc[tm][tn], 0, 0, 0);
  };

  // ---- GEMM1 pipeline. Hazards: abuf (kt+1)&1 / bbuf (kt+2)%3 written at step
  // kt were last ds_read at step kt-1; lgkmcnt(0)+barrier at step kt protect.
  issueA(0, 0); issueB(0, 0); issueB(1, 1);
#pragma unroll
  for (int kt = 0; kt < 32; ++kt) {
    if (kt < 31) asm volatile("s_waitcnt vmcnt(2) lgkmcnt(0)" ::: "memory");
    else         asm volatile("s_waitcnt vmcnt(0) lgkmcnt(0)" ::: "memory");
    __builtin_amdgcn_s_barrier();
    asm volatile("" ::: "memory");        // keep loads/ds_reads below the barrier
    if (kt < 31) issueA(kt + 1, (kt + 1) & 1);
    if (kt < 30) issueB(kt + 2, (kt + 2) % 3);
    __builtin_amdgcn_s_setprio(1);
    compute1(kt & 1, kt % 3);
    __builtin_amdgcn_s_setprio(0);
  }
  __syncthreads();   // all buf reads done; smem region becomes vt

  // ---- v += bias, cast bf16, swizzled into vt (256 rows x 512B = 128KB) ----
  char* vt = smem;
#pragma unroll
  for (int tm = 0; tm < 8; ++tm)
#pragma unroll
    for (int r = 0; r < 4; ++r) {
      int rr = (wm << 7) + tm * 16 + ((l >> 4) << 2) + r;   // c-local 0..255
      float bkv = bias[ct * 256 + rr];
#pragma unroll
      for (int tn = 0; tn < 4; ++tn) {
        int n = (wn << 6) + tn * 16 + (l & 15);
        int ch = (n >> 3) ^ (rr & 7);
        *(bf16*)(vt + rr * 512 + ch * 16 + ((n & 7) << 1)) = (bf16)(acc[tm][tn][r] + bkv);
      }
    }

  auto loadB2 = [&](int kt, bf16x8 (&bb)[4]) {
    const bf16* p = attn + (size_t)((wn << 6) + (l & 15)) * N_ + kt * 32 + ((l >> 4) << 3);
#pragma unroll
    for (int t = 0; t < 4; ++t) bb[t] = *(const bf16x8*)(p + (size_t)t * 16 * N_);
  };
  auto compute2 = [&](int kt, bf16x8 (&bb)[4]) {
    bf16x8 af[8];
#pragma unroll
    for (int t = 0; t < 8; ++t) {
      int m = (wm << 7) + t * 16 + (l & 15);
      int ch = ((kt << 2) + (l >> 4)) ^ (m & 7);
      af[t] = *(const bf16x8*)(vt + m * 512 + (ch << 4));
    }
#pragma unroll
    for (int tm = 0; tm < 8; ++tm)
#pragma unroll
      for (int tn = 0; tn < 4; ++tn)
        acc[tm][tn] = __builtin_amdgcn_mfma_f32_16x16x32_bf16(af[tm], bb[tn], acc[tm][tn], 0, 0, 0);
  };

  // ---- GEMM2: o[256][256] = vt @ attn^T over K=256, reg-prefetch, no barriers ----
  bf16x8 bfA[4], bfB[4];
  loadB2(0, bfA);          // issued before barrier; drained by it
  __syncthreads();         // vt visible
#pragma unroll
  for (int i = 0; i < 8; ++i)
#pragma unroll
    for (int j = 0; j < 4; ++j) acc[i][j] = z;
  for (int kt = 0; kt < 8; kt += 2) {
    loadB2(kt + 1, bfB);
    compute2(kt, bfA);
    if (kt + 2 < 8) loadB2(kt + 2, bfA);
    compute2(kt + 1, bfB);
  }

  // ---- epilogue: out = gamma*o + x ----
#pragma unroll
  for (int tm = 0; tm < 8; ++tm)
#pragma unroll
    for (int tn = 0; tn < 4; ++tn)
#pragma unroll
      for (int r = 0; r < 4; ++r) {
        int rr = (wm << 7) + tm * 16 + ((l >> 4) << 2) + r;
        int m = (wn << 6) + tn * 16 + (l & 15);
        int idx2 = rr * N_ + m;
        o[idx2] = gamma * acc[tm][tn][r] + xin[idx2];
      }
}

__global__ __launch_bounds__(256) void k_fallback(const float4* __restrict__ x,
                                                  const float4* __restrict__ y,
                                                  float4* __restrict__ out) {
  size_t i = (size_t)blockIdx.x * 256 + threadIdx.x;
  out[i] = x[i];
  out[4194304 + i] = y[i];
}

extern "C" void kernel_launch(void* const* d_in, const int* in_sizes, int n_in,
                              void* d_out, int out_size, void* d_ws, size_t ws_size,
                              hipStream_t stream) {
  const float* x   = (const float*)d_in[0];
  const float* y   = (const float*)d_in[1];
  const float* wk1 = (const float*)d_in[2];
  const float* bk1 = (const float*)d_in[3];
  const float* wk2 = (const float*)d_in[4];
  const float* bk2 = (const float*)d_in[5];
  const float* wv1 = (const float*)d_in[6];
  const float* bv1 = (const float*)d_in[7];
  const float* wv2 = (const float*)d_in[8];
  const float* bv2 = (const float*)d_in[9];
  const float* g1  = (const float*)d_in[10];
  const float* g2  = (const float*)d_in[11];
  float* out = (float*)d_out;

  if (ws_size < WS_NEEDED) {
    k_fallback<<<16384, 256, 0, stream>>>((const float4*)x, (const float4*)y, (float4*)out);
    return;
  }

  char* ws = (char*)d_ws;
  bf16* xbT  = (bf16*)(ws + OFF_XBT);
  bf16* ybT  = (bf16*)(ws + OFF_YBT);
  bf16* wk1b = (bf16*)(ws + OFF_WK1);
  bf16* wk2b = (bf16*)(ws + OFF_WK2);
  bf16* wv1b = (bf16*)(ws + OFF_WV1);
  bf16* wv2b = (bf16*)(ws + OFF_WV2);
  bf16* axp  = (bf16*)(ws + OFF_AX);
  bf16* ayp  = (bf16*)(ws + OFF_AY);
  // kxT/kyT in the dead out_y region (overwritten later by k_vapply's out_y)
  bf16* kxT = (bf16*)((char*)out + (size_t)B_ * C_ * N_ * 4);
  bf16* kyT = (bf16*)((char*)out + (size_t)B_ * C_ * N_ * 4 + 4194304);

  k_xpose<<<dim3(4, 16, 128), 256, 0, stream>>>(x, y, xbT, ybT);
  k_cvt4<<<2304, 256, 0, stream>>>(wk1, wk2, wk1b, wk2b, wv1, wv2, wv1b, wv2b);
  k_projk<<<dim3(2, 2, 64), 256, 0, stream>>>(xbT, ybT, wk1b, wk2b, bk1, bk2, kxT, kyT);
  k_esoft<<<dim3(2, 2, 64), 256, 0, stream>>>(kxT, kyT, axp, ayp);
  k_vapply<<<512, 512, 0, stream>>>(xbT, ybT, wv1b, wv2b, bv1, bv2,
                                    axp, ayp, x, y, g1, g2, out);
}